// Round 2
// baseline (334.570 us; speedup 1.0000x reference)
//
#include <hip/hip_runtime.h>
#include <hip/hip_bf16.h>

typedef __hip_bfloat16 bf16;
typedef short short8 __attribute__((ext_vector_type(8)));
typedef float f32x4 __attribute__((ext_vector_type(4)));
typedef float f32x2 __attribute__((ext_vector_type(2)));

#define NPB 256          // nodes per bucket (coarse radix = dst>>8)
#define MAXBUK 1024      // supports N <= 262144

__device__ __forceinline__ float bf2f_raw(unsigned short u) {
    unsigned x = ((unsigned)u) << 16; float f; __builtin_memcpy(&f, &x, 4); return f;
}
__device__ __forceinline__ unsigned short f2bf_raw(float f) {   // RNE
    unsigned u; __builtin_memcpy(&u, &f, 4);
    u += 0x7FFFu + ((u >> 16) & 1u);
    return (unsigned short)(u >> 16);
}
__device__ __forceinline__ float lo_f(unsigned u) {
    unsigned x = u << 16; float f; __builtin_memcpy(&f, &x, 4); return f;
}
__device__ __forceinline__ float hi_f(unsigned u) {
    unsigned x = u & 0xffff0000u; float f; __builtin_memcpy(&f, &x, 4); return f;
}

// ---------------- dtype sniffer: flag=1 if float arrays are f32, 0 if bf16 ----------------

__global__ __launch_bounds__(1024) void sniff_kernel(const unsigned short* __restrict__ w,
                                                     int nshorts, int* __restrict__ flag) {
    __shared__ int red[1024];
    const int t = threadIdx.x;
    int c = 0;
    for (int i = t; i < nshorts; i += 1024) {
        unsigned e = (w[i] >> 7) & 0xFFu;
        if (e >= 140u || (e >= 1u && e <= 40u)) c++;
    }
    red[t] = c;
    __syncthreads();
    for (int o = 512; o > 0; o >>= 1) {
        if (t < o) red[t] += red[t + o];
        __syncthreads();
    }
    if (t == 0) *flag = (red[0] > nshorts / 8) ? 1 : 0;
}

// ---------------- prep: biases->f32; W1/W2 -> MFMA B-fragment-linear bf16 ----------------
// Fragment (16x16x32 bf16 B-operand): lane l holds B[k=(l>>4)*8+j][n=l&15], j=0..7.

__global__ __launch_bounds__(256) void prep_kernel(const void* __restrict__ W1p,
                                                   const void* __restrict__ W2p,
                                                   const void* __restrict__ b1p,
                                                   const void* __restrict__ b2p,
                                                   unsigned short* __restrict__ WB1,
                                                   unsigned short* __restrict__ WB2,
                                                   float* __restrict__ b1f,
                                                   float* __restrict__ b2f,
                                                   const int* __restrict__ flag) {
    const int isf32 = *flag;
    const int t = blockIdx.x * 256 + threadIdx.x;
    const int T1 = 16384, T2 = 8192;
    if (t < T1) {
        int j = t & 7, l = (t >> 3) & 63, f = t >> 9;
        int n = f >> 2, kk = f & 3;
        int k = kk * 32 + (l >> 4) * 8 + j;
        int col = n * 16 + (l & 15);
        WB1[t] = isf32 ? f2bf_raw(((const float*)W1p)[k * 128 + col])
                       : ((const unsigned short*)W1p)[k * 128 + col];
    } else if (t < T1 + T2) {
        int o = t - T1;
        int j = o & 7, l = (o >> 3) & 63, f = o >> 9;
        int n = f >> 2, kk = f & 3;
        int k = kk * 32 + (l >> 4) * 8 + j;
        int col = n * 16 + (l & 15);
        WB2[o] = isf32 ? f2bf_raw(((const float*)W2p)[k * 64 + col])
                       : ((const unsigned short*)W2p)[k * 64 + col];
    } else if (t < T1 + T2 + 128) {
        int o = t - T1 - T2;
        b1f[o] = isf32 ? ((const float*)b1p)[o] : bf2f_raw(((const unsigned short*)b1p)[o]);
    } else if (t < T1 + T2 + 192) {
        int o = t - T1 - T2 - 128;
        b2f[o] = isf32 ? ((const float*)b2p)[o] : bf2f_raw(((const unsigned short*)b2p)[o]);
    }
}

// ---------------- CSR build, bucket-granular ----------------
// 1) ms_count: per-block LDS bucket histogram -> global bucket totals.

__global__ __launch_bounds__(256) void ms_count_kernel(const int* __restrict__ dst,
                                                       int* __restrict__ bktcnt,
                                                       int E, int nbuk) {
    __shared__ int cnt[MAXBUK];
    const int t = threadIdx.x;
    const int e0 = blockIdx.x * 4096;
    const int e1 = min(E, e0 + 4096);
    for (int b = t; b < nbuk; b += 256) cnt[b] = 0;
    __syncthreads();
    for (int e = e0 + t; e < e1; e += 256) atomicAdd(&cnt[dst[e] >> 8], 1);
    __syncthreads();
    for (int b = t; b < nbuk; b += 256) {
        int c = cnt[b];
        if (c) atomicAdd(&bktcnt[b], c);
    }
}

// 2) bscan: exclusive scan of bucket totals -> bofs/bcur.
__global__ __launch_bounds__(1024) void bscan_kernel(const int* __restrict__ bktcnt,
                                                     int* __restrict__ bofs,
                                                     int* __restrict__ bcur,
                                                     int nbuk, int total) {
    __shared__ int ps[1024];
    const int t = threadIdx.x;
    int v = (t < nbuk) ? bktcnt[t] : 0;
    ps[t] = v;
    __syncthreads();
    for (int o = 1; o < 1024; o <<= 1) {
        int u = (t >= o) ? ps[t - o] : 0;
        __syncthreads();
        ps[t] += u;
        __syncthreads();
    }
    if (t < nbuk) {
        int ex = ps[t] - v;
        bofs[t] = ex;
        bcur[t] = ex;
    }
    if (t == 0) bofs[nbuk] = total;
}

// 3) ms_scatter: bin edges into per-bucket contiguous chunks (packed = (dst&255)<<24 | src).
__global__ __launch_bounds__(256) void ms_scatter_kernel(const int* __restrict__ src,
                                                         const int* __restrict__ dst,
                                                         int* __restrict__ bcur,
                                                         unsigned* __restrict__ packed,
                                                         int E, int nbuk) {
    __shared__ int cnt[MAXBUK];
    __shared__ int gbase[MAXBUK];
    const int t = threadIdx.x;
    const int e0 = blockIdx.x * 4096;
    const int e1 = min(E, e0 + 4096);
    for (int b = t; b < nbuk; b += 256) cnt[b] = 0;
    __syncthreads();
    for (int e = e0 + t; e < e1; e += 256) atomicAdd(&cnt[dst[e] >> 8], 1);
    __syncthreads();
    for (int b = t; b < nbuk; b += 256) {
        int c = cnt[b];
        gbase[b] = c ? atomicAdd(&bcur[b], c) : 0;
        cnt[b] = 0;
    }
    __syncthreads();
    for (int e = e0 + t; e < e1; e += 256) {
        int d = dst[e];
        int b = d >> 8;
        int r = atomicAdd(&cnt[b], 1);
        packed[gbase[b] + r] = ((unsigned)(d & 255) << 24) | (unsigned)src[e];
    }
}

// 4) csr_fine2: one block per bucket. Local histogram -> per-node nmeta {base,deg} + dinv; place edges.
__global__ __launch_bounds__(256) void csr_fine2_kernel(const unsigned* __restrict__ packed,
                                                        const int* __restrict__ bofs,
                                                        uint2* __restrict__ nmeta,
                                                        float* __restrict__ dinv,
                                                        int* __restrict__ csrc, int n) {
    __shared__ int cnt2[NPB];
    __shared__ int cur[NPB];
    const int t = threadIdx.x;
    const int b = blockIdx.x;
    const int node0 = b << 8;
    const int nn = min(NPB, n - node0);
    cnt2[t] = 0;
    __syncthreads();
    const int beg = bofs[b], end = bofs[b + 1];
    for (int i = beg + t; i < end; i += 256) atomicAdd(&cnt2[packed[i] >> 24], 1);
    __syncthreads();
    int c = cnt2[t];
    cur[t] = c;
    __syncthreads();
    for (int o = 1; o < 256; o <<= 1) {        // inclusive scan over 256 local counts
        int u = (t >= o) ? cur[t - o] : 0;
        __syncthreads();
        cur[t] += u;
        __syncthreads();
    }
    const int base = beg + cur[t] - c;          // exclusive
    if (t < nn) {
        nmeta[node0 + t] = make_uint2((unsigned)base, (unsigned)c);
        dinv[node0 + t] = rsqrtf((float)(c + 1));
    }
    __syncthreads();
    cur[t] = base;
    __syncthreads();
    for (int i = beg + t; i < end; i += 256) {
        unsigned u = packed[i];
        int pos = atomicAdd(&cur[u >> 24], 1);
        csrc[pos] = (int)(u & 0xFFFFFFu);
    }
}

// 5) wsrc: per-edge source normalization weight, wsrc[j] = dinv[csrc[j]].
__global__ __launch_bounds__(256) void wsrc_kernel(const int* __restrict__ csrc,
                                                   const float* __restrict__ dinv,
                                                   float* __restrict__ wsrc, int E) {
    int i = blockIdx.x * 256 + threadIdx.x;
    if (i < E) wsrc[i] = dinv[csrc[i]];
}

// ---------------- GEMM1 (MFMA): H[nrows x 128] = X * W1, bf16 out (runtime dtype) ----------------

__global__ __launch_bounds__(256) void gemm1_mfma(const void* __restrict__ Xp,
                                                  const unsigned short* __restrict__ WB1,
                                                  unsigned short* __restrict__ H, int nrows,
                                                  const int* __restrict__ flag) {
    __shared__ __align__(16) unsigned short Xs[128 * 136];
    __shared__ __align__(16) unsigned short Cs[128 * 68];
    const int t = threadIdx.x;
    const int r0 = blockIdx.x * 128;
    const int isf32 = *flag;

    if (isf32) {
        const float4* Xg = (const float4*)Xp;
        #pragma unroll
        for (int i = 0; i < 16; ++i) {
            int idx = t + 256 * i;
            int row = idx >> 5, c4 = idx & 31;
            float4 v = {0.f, 0.f, 0.f, 0.f};
            if (r0 + row < nrows) v = Xg[(size_t)(r0 + row) * 32 + c4];
            unsigned lo = (unsigned)f2bf_raw(v.x) | ((unsigned)f2bf_raw(v.y) << 16);
            unsigned hi = (unsigned)f2bf_raw(v.z) | ((unsigned)f2bf_raw(v.w) << 16);
            *reinterpret_cast<uint2*>(&Xs[row * 136 + c4 * 4]) = make_uint2(lo, hi);
        }
    } else {
        const uint4* Xg = (const uint4*)Xp;
        #pragma unroll
        for (int i = 0; i < 8; ++i) {
            int idx = t + 256 * i;
            int row = idx >> 4, c8 = idx & 15;
            uint4 v = {0u, 0u, 0u, 0u};
            if (r0 + row < nrows) v = Xg[(size_t)(r0 + row) * 16 + c8];
            *reinterpret_cast<uint4*>(&Xs[row * 136 + c8 * 8]) = v;
        }
    }
    __syncthreads();

    const int lane = t & 63, w = t >> 6;
    const int m0 = w * 32;
    short8 a[2][4];
    #pragma unroll
    for (int rt = 0; rt < 2; ++rt)
        #pragma unroll
        for (int kk = 0; kk < 4; ++kk)
            a[rt][kk] = *reinterpret_cast<const short8*>(
                &Xs[(m0 + rt * 16 + (lane & 15)) * 136 + kk * 32 + (lane >> 4) * 8]);

    for (int p = 0; p < 2; ++p) {
        short8 b[4][4];
        #pragma unroll
        for (int n = 0; n < 4; ++n)
            #pragma unroll
            for (int kk = 0; kk < 4; ++kk)
                b[n][kk] = *reinterpret_cast<const short8*>(
                    WB1 + (size_t)(((p * 4 + n) * 4 + kk) * 64 + lane) * 8);
        f32x4 acc[2][4];
        #pragma unroll
        for (int rt = 0; rt < 2; ++rt)
            #pragma unroll
            for (int n = 0; n < 4; ++n) {
                acc[rt][n] = (f32x4){0.f, 0.f, 0.f, 0.f};
                #pragma unroll
                for (int kk = 0; kk < 4; ++kk)
                    acc[rt][n] = __builtin_amdgcn_mfma_f32_16x16x32_bf16(
                        a[rt][kk], b[n][kk], acc[rt][n], 0, 0, 0);
            }
        if (p) __syncthreads();
        #pragma unroll
        for (int rt = 0; rt < 2; ++rt)
            #pragma unroll
            for (int n = 0; n < 4; ++n)
                #pragma unroll
                for (int r = 0; r < 4; ++r) {
                    int row = m0 + rt * 16 + (lane >> 4) * 4 + r;
                    Cs[row * 68 + n * 16 + (lane & 15)] = f2bf_raw(acc[rt][n][r]);
                }
        __syncthreads();
        #pragma unroll
        for (int i = 0; i < 8; ++i) {
            int idx = t + 256 * i;
            int row = idx >> 4, c4 = idx & 15;
            if (r0 + row < nrows) {
                uint2 v = *reinterpret_cast<const uint2*>(&Cs[row * 68 + c4 * 4]);
                *reinterpret_cast<uint2*>(H + (size_t)(r0 + row) * 128 + p * 64 + c4 * 4) = v;
            }
        }
        if (!p) __syncthreads();
    }
}

// ---------------- Aggregation v4: wave-per-node, single predicated 16-deep round ----------------
// Lane l: group g=l>>4 handles edge slots j+g, j+4+g, j+8+g, j+12+g; sub=l&15 covers 16B chunk.
// Pad slots clamp the index (L1-hit on a row this node already gathers) with weight 0.
// Avg rounds/node drops from ~2.5 (8/4/tail) to ~1.44. 4 dwordx4 gathers in flight per lane.

__device__ __forceinline__ void acc8v(f32x2* acc, uint4 v, float w) {
    f32x2 wv = {w, w};
    acc[0] += (f32x2){lo_f(v.x), hi_f(v.x)} * wv;
    acc[1] += (f32x2){lo_f(v.y), hi_f(v.y)} * wv;
    acc[2] += (f32x2){lo_f(v.z), hi_f(v.z)} * wv;
    acc[3] += (f32x2){lo_f(v.w), hi_f(v.w)} * wv;
}

template <bool RELU_BIAS>
__global__ __launch_bounds__(256) void agg128_v4(const uint4* __restrict__ H4,
                                                 const uint2* __restrict__ nmeta,
                                                 const int* __restrict__ csrc,
                                                 const float* __restrict__ wsrc,
                                                 const float* __restrict__ biasf,
                                                 uint4* __restrict__ G4, int n) {
    const int lane = threadIdx.x & 63;
    const int g = lane >> 4;
    const int sub = lane & 15;
    const int node = blockIdx.x * 4 + (threadIdx.x >> 6);
    if (node >= n) return;
    const uint2 meta = nmeta[node];
    const int base = (int)meta.x;
    const int cnt = (int)meta.y;
    const int end = base + cnt;
    const float di = rsqrtf((float)(cnt + 1));

    f32x2 acc[4];
    {   // self-loop term: all groups load the (shared, cached) row; only group 0 weighs it
        const float ws = (g == 0) ? di * di : 0.f;
        uint4 v = H4[(size_t)node * 16 + sub];
        acc[0] = (f32x2){ws * lo_f(v.x), ws * hi_f(v.x)};
        acc[1] = (f32x2){ws * lo_f(v.y), ws * hi_f(v.y)};
        acc[2] = (f32x2){ws * lo_f(v.z), ws * hi_f(v.z)};
        acc[3] = (f32x2){ws * lo_f(v.w), ws * hi_f(v.w)};
    }

    for (int j = base; j < end; j += 16) {
        const int lim = end - 1;
        int i0 = j + g, i1 = j + 4 + g, i2 = j + 8 + g, i3 = j + 12 + g;
        int c0 = min(i0, lim), c1 = min(i1, lim), c2 = min(i2, lim), c3 = min(i3, lim);
        int s0 = csrc[c0], s1 = csrc[c1], s2 = csrc[c2], s3 = csrc[c3];
        float w0 = (i0 <= lim) ? di * wsrc[c0] : 0.f;
        float w1 = (i1 <= lim) ? di * wsrc[c1] : 0.f;
        float w2 = (i2 <= lim) ? di * wsrc[c2] : 0.f;
        float w3 = (i3 <= lim) ? di * wsrc[c3] : 0.f;
        uint4 v0 = H4[(size_t)s0 * 16 + sub];
        uint4 v1 = H4[(size_t)s1 * 16 + sub];
        uint4 v2 = H4[(size_t)s2 * 16 + sub];
        uint4 v3 = H4[(size_t)s3 * 16 + sub];
        acc8v(acc, v0, w0);
        acc8v(acc, v1, w1);
        acc8v(acc, v2, w2);
        acc8v(acc, v3, w3);
    }

    float a8[8];
    #pragma unroll
    for (int i = 0; i < 4; ++i) { a8[2 * i] = acc[i].x; a8[2 * i + 1] = acc[i].y; }
    #pragma unroll
    for (int i = 0; i < 8; ++i) {      // combine the 4 edge-groups
        a8[i] += __shfl_xor(a8[i], 16, 64);
        a8[i] += __shfl_xor(a8[i], 32, 64);
    }

    if (g == 0) {
        if (RELU_BIAS) {
            const float4* b4 = (const float4*)biasf;
            float4 blo = b4[sub * 2], bhi = b4[sub * 2 + 1];
            a8[0] = fmaxf(a8[0] + blo.x, 0.f);
            a8[1] = fmaxf(a8[1] + blo.y, 0.f);
            a8[2] = fmaxf(a8[2] + blo.z, 0.f);
            a8[3] = fmaxf(a8[3] + blo.w, 0.f);
            a8[4] = fmaxf(a8[4] + bhi.x, 0.f);
            a8[5] = fmaxf(a8[5] + bhi.y, 0.f);
            a8[6] = fmaxf(a8[6] + bhi.z, 0.f);
            a8[7] = fmaxf(a8[7] + bhi.w, 0.f);
        }
        uint4 o;
        o.x = (unsigned)f2bf_raw(a8[0]) | ((unsigned)f2bf_raw(a8[1]) << 16);
        o.y = (unsigned)f2bf_raw(a8[2]) | ((unsigned)f2bf_raw(a8[3]) << 16);
        o.z = (unsigned)f2bf_raw(a8[4]) | ((unsigned)f2bf_raw(a8[5]) << 16);
        o.w = (unsigned)f2bf_raw(a8[6]) | ((unsigned)f2bf_raw(a8[7]) << 16);
        G4[(size_t)node * 16 + sub] = o;
    }
}

// ---------------- GEMM2 (MFMA) + bias + log_softmax (runtime output dtype) ----------------

__global__ __launch_bounds__(256) void gemm2_mfma(const unsigned short* __restrict__ X,
                                                  const unsigned short* __restrict__ WB2,
                                                  const float* __restrict__ b2f,
                                                  void* __restrict__ OUTv, int nrows,
                                                  const int* __restrict__ flag) {
    __shared__ __align__(16) unsigned short Xs[128 * 136];
    const int t = threadIdx.x;
    const int r0 = blockIdx.x * 128;
    const int outf32 = *flag;

    const uint4* Xg = (const uint4*)X;
    #pragma unroll
    for (int i = 0; i < 8; ++i) {
        int idx = t + 256 * i;
        int row = idx >> 4, c8 = idx & 15;
        uint4 v = {0u, 0u, 0u, 0u};
        if (r0 + row < nrows) v = Xg[(size_t)(r0 + row) * 16 + c8];
        *reinterpret_cast<uint4*>(&Xs[row * 136 + c8 * 8]) = v;
    }
    __syncthreads();

    const int lane = t & 63, w = t >> 6;
    const int m0 = w * 32;
    short8 a[2][4];
    #pragma unroll
    for (int rt = 0; rt < 2; ++rt)
        #pragma unroll
        for (int kk = 0; kk < 4; ++kk)
            a[rt][kk] = *reinterpret_cast<const short8*>(
                &Xs[(m0 + rt * 16 + (lane & 15)) * 136 + kk * 32 + (lane >> 4) * 8]);

    short8 b[4][4];
    #pragma unroll
    for (int n = 0; n < 4; ++n)
        #pragma unroll
        for (int kk = 0; kk < 4; ++kk)
            b[n][kk] = *reinterpret_cast<const short8*>(
                WB2 + (size_t)((n * 4 + kk) * 64 + lane) * 8);

    f32x4 acc[2][4];
    #pragma unroll
    for (int rt = 0; rt < 2; ++rt)
        #pragma unroll
        for (int n = 0; n < 4; ++n) {
            acc[rt][n] = (f32x4){0.f, 0.f, 0.f, 0.f};
            #pragma unroll
            for (int kk = 0; kk < 4; ++kk)
                acc[rt][n] = __builtin_amdgcn_mfma_f32_16x16x32_bf16(
                    a[rt][kk], b[n][kk], acc[rt][n], 0, 0, 0);
        }

    float bc[4];
    #pragma unroll
    for (int n = 0; n < 4; ++n) bc[n] = b2f[n * 16 + (lane & 15)];
    #pragma unroll
    for (int rt = 0; rt < 2; ++rt)
        #pragma unroll
        for (int n = 0; n < 4; ++n)
            #pragma unroll
            for (int r = 0; r < 4; ++r) acc[rt][n][r] += bc[n];

    float lse[2][4];
    #pragma unroll
    for (int rt = 0; rt < 2; ++rt)
        #pragma unroll
        for (int r = 0; r < 4; ++r) {
            float m = fmaxf(fmaxf(acc[rt][0][r], acc[rt][1][r]),
                            fmaxf(acc[rt][2][r], acc[rt][3][r]));
            #pragma unroll
            for (int o = 1; o < 16; o <<= 1) m = fmaxf(m, __shfl_xor(m, o, 64));
            float s = __expf(acc[rt][0][r] - m) + __expf(acc[rt][1][r] - m) +
                      __expf(acc[rt][2][r] - m) + __expf(acc[rt][3][r] - m);
            #pragma unroll
            for (int o = 1; o < 16; o <<= 1) s += __shfl_xor(s, o, 64);
            lse[rt][r] = m + __logf(s);
        }

    const int colb = lane & 15, q = lane >> 4;
    #pragma unroll
    for (int rt = 0; rt < 2; ++rt)
        #pragma unroll
        for (int r = 0; r < 4; ++r) {
            int grow = r0 + m0 + rt * 16 + q * 4 + r;
            if (grow < nrows) {
                if (outf32) {
                    float* Of = (float*)OUTv;
                    #pragma unroll
                    for (int n = 0; n < 4; ++n)
                        Of[(size_t)grow * 64 + n * 16 + colb] = acc[rt][n][r] - lse[rt][r];
                } else {
                    unsigned short* Ob = (unsigned short*)OUTv;
                    #pragma unroll
                    for (int n = 0; n < 4; ++n)
                        Ob[(size_t)grow * 64 + n * 16 + colb] = f2bf_raw(acc[rt][n][r] - lse[rt][r]);
                }
            }
        }
}

// ---------------- launch ----------------

extern "C" void kernel_launch(void* const* d_in, const int* in_sizes, int n_in,
                              void* d_out, int out_size, void* d_ws, size_t ws_size,
                              hipStream_t stream) {
    const void* x  = d_in[0];
    const int*  ei = (const int*)d_in[1];
    const void* W1 = d_in[2];
    const void* b1 = d_in[3];
    const void* W2 = d_in[4];
    const void* b2 = d_in[5];

    const int N = in_sizes[0] / 128;
    const int E = in_sizes[1] / 2;
    const int* src = ei;
    const int* dst = ei + E;
    const int NBUK = (N + NPB - 1) / NPB;     // 391 for N=100K

    char* p = (char*)d_ws;
    auto alloc = [&](size_t bytes) { char* q = p; p += (bytes + 255) & ~255ull; return q; };
    int*   flag   = (int*)  alloc(4);
    uint2* nmeta  = (uint2*)alloc((size_t)N * 8);
    float* dinv   = (float*)alloc((size_t)N * 4);
    int*   bktcnt = (int*)  alloc((size_t)NBUK * 4);
    int*   bofs   = (int*)  alloc((size_t)(NBUK + 1) * 4);
    int*   bcur   = (int*)  alloc((size_t)NBUK * 4);
    float* b1f    = (float*)alloc(128 * 4);
    float* b2f    = (float*)alloc(64 * 4);
    unsigned short* WB1 = (unsigned short*)alloc(16384 * 2);
    unsigned short* WB2 = (unsigned short*)alloc(8192 * 2);
    unsigned* big = (unsigned*)alloc((size_t)N * 128 * 2);   // h1, later a2 (row-major)
    unsigned* packed = (unsigned*)d_out;          // 6.4 MB scratch in d_out (dead after csr_fine2)
    float*    wsrc   = (float*)d_out;             // reuses packed's space after it dies
    int*      csrc   = (int*)d_out + E;           // 6.4 MB scratch in d_out
    unsigned* g1 = (unsigned*)d_in[0];            // g1 into x's buffer (x dead after gemm1)
    (void)ws_size; (void)n_in; (void)out_size;

    hipMemsetAsync(bktcnt, 0, (size_t)NBUK * 4, stream);
    sniff_kernel<<<1, 1024, 0, stream>>>((const unsigned short*)W1, in_sizes[2], flag);
    prep_kernel<<<97, 256, 0, stream>>>(W1, W2, b1, b2, WB1, WB2, b1f, b2f, flag);
    const int MSB = (E + 4095) / 4096;
    ms_count_kernel<<<MSB, 256, 0, stream>>>(dst, bktcnt, E, NBUK);
    bscan_kernel<<<1, 1024, 0, stream>>>(bktcnt, bofs, bcur, NBUK, E);
    ms_scatter_kernel<<<MSB, 256, 0, stream>>>(src, dst, bcur, packed, E, NBUK);
    csr_fine2_kernel<<<NBUK, 256, 0, stream>>>(packed, bofs, nmeta, dinv, csrc, N);
    wsrc_kernel<<<(E + 255) / 256, 256, 0, stream>>>(csrc, dinv, wsrc, E);

    const int GB = (N + 127) / 128;
    gemm1_mfma<<<GB, 256, 0, stream>>>(x, WB1, (unsigned short*)big, N, flag);
    agg128_v4<true><<<(N + 3) / 4, 256, 0, stream>>>((const uint4*)big, nmeta, csrc, wsrc, b1f, (uint4*)g1, N);
    agg128_v4<false><<<(N + 3) / 4, 256, 0, stream>>>((const uint4*)g1, nmeta, csrc, wsrc, nullptr, (uint4*)big, N);
    gemm2_mfma<<<GB, 256, 0, stream>>>((const unsigned short*)big, WB2, b2f, d_out, N, flag);
}

// Round 3
// 332.262 us; speedup vs baseline: 1.0069x; 1.0069x over previous
//
#include <hip/hip_runtime.h>
#include <hip/hip_bf16.h>

typedef __hip_bfloat16 bf16;
typedef short short8 __attribute__((ext_vector_type(8)));
typedef float f32x4 __attribute__((ext_vector_type(4)));
typedef float f32x2 __attribute__((ext_vector_type(2)));

#define NPB 256          // nodes per bucket (coarse radix = dst>>8)
#define MAXBUK 1024      // supports N <= 262144

__device__ __forceinline__ float bf2f_raw(unsigned short u) {
    unsigned x = ((unsigned)u) << 16; float f; __builtin_memcpy(&f, &x, 4); return f;
}
__device__ __forceinline__ unsigned short f2bf_raw(float f) {   // RNE
    unsigned u; __builtin_memcpy(&u, &f, 4);
    u += 0x7FFFu + ((u >> 16) & 1u);
    return (unsigned short)(u >> 16);
}
__device__ __forceinline__ float lo_f(unsigned u) {
    unsigned x = u << 16; float f; __builtin_memcpy(&f, &x, 4); return f;
}
__device__ __forceinline__ float hi_f(unsigned u) {
    unsigned x = u & 0xffff0000u; float f; __builtin_memcpy(&f, &x, 4); return f;
}

// ---------------- dtype sniffer: flag=1 if float arrays are f32, 0 if bf16 ----------------

__global__ __launch_bounds__(1024) void sniff_kernel(const unsigned short* __restrict__ w,
                                                     int nshorts, int* __restrict__ flag) {
    __shared__ int red[1024];
    const int t = threadIdx.x;
    int c = 0;
    for (int i = t; i < nshorts; i += 1024) {
        unsigned e = (w[i] >> 7) & 0xFFu;
        if (e >= 140u || (e >= 1u && e <= 40u)) c++;
    }
    red[t] = c;
    __syncthreads();
    for (int o = 512; o > 0; o >>= 1) {
        if (t < o) red[t] += red[t + o];
        __syncthreads();
    }
    if (t == 0) *flag = (red[0] > nshorts / 8) ? 1 : 0;
}

// ---------------- prep: biases->f32; W1/W2 -> MFMA B-fragment-linear bf16 ----------------
// Fragment (16x16x32 bf16 B-operand): lane l holds B[k=(l>>4)*8+j][n=l&15], j=0..7.

__global__ __launch_bounds__(256) void prep_kernel(const void* __restrict__ W1p,
                                                   const void* __restrict__ W2p,
                                                   const void* __restrict__ b1p,
                                                   const void* __restrict__ b2p,
                                                   unsigned short* __restrict__ WB1,
                                                   unsigned short* __restrict__ WB2,
                                                   float* __restrict__ b1f,
                                                   float* __restrict__ b2f,
                                                   const int* __restrict__ flag) {
    const int isf32 = *flag;
    const int t = blockIdx.x * 256 + threadIdx.x;
    const int T1 = 16384, T2 = 8192;
    if (t < T1) {
        int j = t & 7, l = (t >> 3) & 63, f = t >> 9;
        int n = f >> 2, kk = f & 3;
        int k = kk * 32 + (l >> 4) * 8 + j;
        int col = n * 16 + (l & 15);
        WB1[t] = isf32 ? f2bf_raw(((const float*)W1p)[k * 128 + col])
                       : ((const unsigned short*)W1p)[k * 128 + col];
    } else if (t < T1 + T2) {
        int o = t - T1;
        int j = o & 7, l = (o >> 3) & 63, f = o >> 9;
        int n = f >> 2, kk = f & 3;
        int k = kk * 32 + (l >> 4) * 8 + j;
        int col = n * 16 + (l & 15);
        WB2[o] = isf32 ? f2bf_raw(((const float*)W2p)[k * 64 + col])
                       : ((const unsigned short*)W2p)[k * 64 + col];
    } else if (t < T1 + T2 + 128) {
        int o = t - T1 - T2;
        b1f[o] = isf32 ? ((const float*)b1p)[o] : bf2f_raw(((const unsigned short*)b1p)[o]);
    } else if (t < T1 + T2 + 192) {
        int o = t - T1 - T2 - 128;
        b2f[o] = isf32 ? ((const float*)b2p)[o] : bf2f_raw(((const unsigned short*)b2p)[o]);
    }
}

// ---------------- CSR build, bucket-granular ----------------
// 1) ms_count: per-block LDS bucket histogram -> global bucket totals.

__global__ __launch_bounds__(256) void ms_count_kernel(const int* __restrict__ dst,
                                                       int* __restrict__ bktcnt,
                                                       int E, int nbuk) {
    __shared__ int cnt[MAXBUK];
    const int t = threadIdx.x;
    const int e0 = blockIdx.x * 4096;
    const int e1 = min(E, e0 + 4096);
    for (int b = t; b < nbuk; b += 256) cnt[b] = 0;
    __syncthreads();
    for (int e = e0 + t; e < e1; e += 256) atomicAdd(&cnt[dst[e] >> 8], 1);
    __syncthreads();
    for (int b = t; b < nbuk; b += 256) {
        int c = cnt[b];
        if (c) atomicAdd(&bktcnt[b], c);
    }
}

// 2) bscan: exclusive scan of bucket totals -> bofs/bcur.
__global__ __launch_bounds__(1024) void bscan_kernel(const int* __restrict__ bktcnt,
                                                     int* __restrict__ bofs,
                                                     int* __restrict__ bcur,
                                                     int nbuk, int total) {
    __shared__ int ps[1024];
    const int t = threadIdx.x;
    int v = (t < nbuk) ? bktcnt[t] : 0;
    ps[t] = v;
    __syncthreads();
    for (int o = 1; o < 1024; o <<= 1) {
        int u = (t >= o) ? ps[t - o] : 0;
        __syncthreads();
        ps[t] += u;
        __syncthreads();
    }
    if (t < nbuk) {
        int ex = ps[t] - v;
        bofs[t] = ex;
        bcur[t] = ex;
    }
    if (t == 0) bofs[nbuk] = total;
}

// 3) ms_scatter: bin edges into per-bucket contiguous chunks (packed = (dst&255)<<24 | src).
__global__ __launch_bounds__(256) void ms_scatter_kernel(const int* __restrict__ src,
                                                         const int* __restrict__ dst,
                                                         int* __restrict__ bcur,
                                                         unsigned* __restrict__ packed,
                                                         int E, int nbuk) {
    __shared__ int cnt[MAXBUK];
    __shared__ int gbase[MAXBUK];
    const int t = threadIdx.x;
    const int e0 = blockIdx.x * 4096;
    const int e1 = min(E, e0 + 4096);
    for (int b = t; b < nbuk; b += 256) cnt[b] = 0;
    __syncthreads();
    for (int e = e0 + t; e < e1; e += 256) atomicAdd(&cnt[dst[e] >> 8], 1);
    __syncthreads();
    for (int b = t; b < nbuk; b += 256) {
        int c = cnt[b];
        gbase[b] = c ? atomicAdd(&bcur[b], c) : 0;
        cnt[b] = 0;
    }
    __syncthreads();
    for (int e = e0 + t; e < e1; e += 256) {
        int d = dst[e];
        int b = d >> 8;
        int r = atomicAdd(&cnt[b], 1);
        packed[gbase[b] + r] = ((unsigned)(d & 255) << 24) | (unsigned)src[e];
    }
}

// 4) csr_fine2: one block per bucket. Local histogram -> per-node nmeta {base,deg} + dinv; place edges.
__global__ __launch_bounds__(256) void csr_fine2_kernel(const unsigned* __restrict__ packed,
                                                        const int* __restrict__ bofs,
                                                        uint2* __restrict__ nmeta,
                                                        float* __restrict__ dinv,
                                                        int* __restrict__ csrc, int n) {
    __shared__ int cnt2[NPB];
    __shared__ int cur[NPB];
    const int t = threadIdx.x;
    const int b = blockIdx.x;
    const int node0 = b << 8;
    const int nn = min(NPB, n - node0);
    cnt2[t] = 0;
    __syncthreads();
    const int beg = bofs[b], end = bofs[b + 1];
    for (int i = beg + t; i < end; i += 256) atomicAdd(&cnt2[packed[i] >> 24], 1);
    __syncthreads();
    int c = cnt2[t];
    cur[t] = c;
    __syncthreads();
    for (int o = 1; o < 256; o <<= 1) {        // inclusive scan over 256 local counts
        int u = (t >= o) ? cur[t - o] : 0;
        __syncthreads();
        cur[t] += u;
        __syncthreads();
    }
    const int base = beg + cur[t] - c;          // exclusive
    if (t < nn) {
        nmeta[node0 + t] = make_uint2((unsigned)base, (unsigned)c);
        dinv[node0 + t] = rsqrtf((float)(c + 1));
    }
    __syncthreads();
    cur[t] = base;
    __syncthreads();
    for (int i = beg + t; i < end; i += 256) {
        unsigned u = packed[i];
        int pos = atomicAdd(&cur[u >> 24], 1);
        csrc[pos] = (int)(u & 0xFFFFFFu);
    }
}

// 5) wsrc: per-edge source normalization weight, wsrc[j] = dinv[csrc[j]].
__global__ __launch_bounds__(256) void wsrc_kernel(const int* __restrict__ csrc,
                                                   const float* __restrict__ dinv,
                                                   float* __restrict__ wsrc, int E) {
    int i = blockIdx.x * 256 + threadIdx.x;
    if (i < E) wsrc[i] = dinv[csrc[i]];
}

// ---------------- GEMM1 (MFMA): H[nrows x 128] = X * W1, bf16 out (runtime dtype) ----------------

__global__ __launch_bounds__(256) void gemm1_mfma(const void* __restrict__ Xp,
                                                  const unsigned short* __restrict__ WB1,
                                                  unsigned short* __restrict__ H, int nrows,
                                                  const int* __restrict__ flag) {
    __shared__ __align__(16) unsigned short Xs[128 * 136];
    __shared__ __align__(16) unsigned short Cs[128 * 68];
    const int t = threadIdx.x;
    const int r0 = blockIdx.x * 128;
    const int isf32 = *flag;

    if (isf32) {
        const float4* Xg = (const float4*)Xp;
        #pragma unroll
        for (int i = 0; i < 16; ++i) {
            int idx = t + 256 * i;
            int row = idx >> 5, c4 = idx & 31;
            float4 v = {0.f, 0.f, 0.f, 0.f};
            if (r0 + row < nrows) v = Xg[(size_t)(r0 + row) * 32 + c4];
            unsigned lo = (unsigned)f2bf_raw(v.x) | ((unsigned)f2bf_raw(v.y) << 16);
            unsigned hi = (unsigned)f2bf_raw(v.z) | ((unsigned)f2bf_raw(v.w) << 16);
            *reinterpret_cast<uint2*>(&Xs[row * 136 + c4 * 4]) = make_uint2(lo, hi);
        }
    } else {
        const uint4* Xg = (const uint4*)Xp;
        #pragma unroll
        for (int i = 0; i < 8; ++i) {
            int idx = t + 256 * i;
            int row = idx >> 4, c8 = idx & 15;
            uint4 v = {0u, 0u, 0u, 0u};
            if (r0 + row < nrows) v = Xg[(size_t)(r0 + row) * 16 + c8];
            *reinterpret_cast<uint4*>(&Xs[row * 136 + c8 * 8]) = v;
        }
    }
    __syncthreads();

    const int lane = t & 63, w = t >> 6;
    const int m0 = w * 32;
    short8 a[2][4];
    #pragma unroll
    for (int rt = 0; rt < 2; ++rt)
        #pragma unroll
        for (int kk = 0; kk < 4; ++kk)
            a[rt][kk] = *reinterpret_cast<const short8*>(
                &Xs[(m0 + rt * 16 + (lane & 15)) * 136 + kk * 32 + (lane >> 4) * 8]);

    for (int p = 0; p < 2; ++p) {
        short8 b[4][4];
        #pragma unroll
        for (int n = 0; n < 4; ++n)
            #pragma unroll
            for (int kk = 0; kk < 4; ++kk)
                b[n][kk] = *reinterpret_cast<const short8*>(
                    WB1 + (size_t)(((p * 4 + n) * 4 + kk) * 64 + lane) * 8);
        f32x4 acc[2][4];
        #pragma unroll
        for (int rt = 0; rt < 2; ++rt)
            #pragma unroll
            for (int n = 0; n < 4; ++n) {
                acc[rt][n] = (f32x4){0.f, 0.f, 0.f, 0.f};
                #pragma unroll
                for (int kk = 0; kk < 4; ++kk)
                    acc[rt][n] = __builtin_amdgcn_mfma_f32_16x16x32_bf16(
                        a[rt][kk], b[n][kk], acc[rt][n], 0, 0, 0);
            }
        if (p) __syncthreads();
        #pragma unroll
        for (int rt = 0; rt < 2; ++rt)
            #pragma unroll
            for (int n = 0; n < 4; ++n)
                #pragma unroll
                for (int r = 0; r < 4; ++r) {
                    int row = m0 + rt * 16 + (lane >> 4) * 4 + r;
                    Cs[row * 68 + n * 16 + (lane & 15)] = f2bf_raw(acc[rt][n][r]);
                }
        __syncthreads();
        #pragma unroll
        for (int i = 0; i < 8; ++i) {
            int idx = t + 256 * i;
            int row = idx >> 4, c4 = idx & 15;
            if (r0 + row < nrows) {
                uint2 v = *reinterpret_cast<const uint2*>(&Cs[row * 68 + c4 * 4]);
                *reinterpret_cast<uint2*>(H + (size_t)(r0 + row) * 128 + p * 64 + c4 * 4) = v;
            }
        }
        if (!p) __syncthreads();
    }
}

// ---------------- Aggregation v5: wave-per-node, 128-thr blocks, 16/8/4/tail cascade ----------------
// Lane l: group g=l>>4 handles edge slot j+4k+g; sub=l&15 covers 16B chunk of the 256B row.
// No pad gathers (v4 lesson: pads cost real TA/L1 slots). 128-thr blocks (2 nodes) raise
// attainable occupancy to 32 waves/CU and cut sibling-wait at block retirement.

__device__ __forceinline__ void acc8v(f32x2* acc, uint4 v, float w) {
    f32x2 wv = {w, w};
    acc[0] += (f32x2){lo_f(v.x), hi_f(v.x)} * wv;
    acc[1] += (f32x2){lo_f(v.y), hi_f(v.y)} * wv;
    acc[2] += (f32x2){lo_f(v.z), hi_f(v.z)} * wv;
    acc[3] += (f32x2){lo_f(v.w), hi_f(v.w)} * wv;
}

template <bool RELU_BIAS>
__global__ __launch_bounds__(128) void agg128_v5(const uint4* __restrict__ H4,
                                                 const uint2* __restrict__ nmeta,
                                                 const int* __restrict__ csrc,
                                                 const float* __restrict__ wsrc,
                                                 const float* __restrict__ biasf,
                                                 uint4* __restrict__ G4, int n) {
    const int lane = threadIdx.x & 63;
    const int g = lane >> 4;
    const int sub = lane & 15;
    const int node = blockIdx.x * 2 + (threadIdx.x >> 6);
    if (node >= n) return;

    // issue self-row gather first (independent of the nmeta->csrc chain)
    const unsigned selfoff = ((unsigned)node << 4) + (unsigned)sub;
    uint4 vself = H4[selfoff];

    const uint2 meta = nmeta[node];
    const int base = (int)meta.x;
    const int cnt = (int)meta.y;
    const int end = base + cnt;
    const float di = rsqrtf((float)(cnt + 1));

    f32x2 acc[4];
    {   // self-loop term: only group 0 weighs it (others carry 0 into the reduce)
        const float ws = (g == 0) ? di * di : 0.f;
        acc[0] = (f32x2){ws * lo_f(vself.x), ws * hi_f(vself.x)};
        acc[1] = (f32x2){ws * lo_f(vself.y), ws * hi_f(vself.y)};
        acc[2] = (f32x2){ws * lo_f(vself.z), ws * hi_f(vself.z)};
        acc[3] = (f32x2){ws * lo_f(vself.w), ws * hi_f(vself.w)};
    }

    int j = base;
    for (; j + 15 < end; j += 16) {          // 16 edges, 4 dwordx4 gathers in flight
        int s0 = csrc[j + g];
        int s1 = csrc[j + 4 + g];
        int s2 = csrc[j + 8 + g];
        int s3 = csrc[j + 12 + g];
        uint4 v0 = H4[((unsigned)s0 << 4) + sub];
        uint4 v1 = H4[((unsigned)s1 << 4) + sub];
        uint4 v2 = H4[((unsigned)s2 << 4) + sub];
        uint4 v3 = H4[((unsigned)s3 << 4) + sub];
        float w0 = di * wsrc[j + g];
        float w1 = di * wsrc[j + 4 + g];
        float w2 = di * wsrc[j + 8 + g];
        float w3 = di * wsrc[j + 12 + g];
        acc8v(acc, v0, w0);
        acc8v(acc, v1, w1);
        acc8v(acc, v2, w2);
        acc8v(acc, v3, w3);
    }
    for (; j + 7 < end; j += 8) {            // 8 edges
        int s0 = csrc[j + g];
        int s1 = csrc[j + 4 + g];
        uint4 v0 = H4[((unsigned)s0 << 4) + sub];
        uint4 v1 = H4[((unsigned)s1 << 4) + sub];
        float w0 = di * wsrc[j + g];
        float w1 = di * wsrc[j + 4 + g];
        acc8v(acc, v0, w0);
        acc8v(acc, v1, w1);
    }
    for (; j + 3 < end; j += 4) {            // 4 edges
        int s0 = csrc[j + g];
        uint4 v0 = H4[((unsigned)s0 << 4) + sub];
        float w0 = di * wsrc[j + g];
        acc8v(acc, v0, w0);
    }
    if (j + g < end) {                       // tail (<4 edges), group-predicated
        int s0 = csrc[j + g];
        uint4 v0 = H4[((unsigned)s0 << 4) + sub];
        float w0 = di * wsrc[j + g];
        acc8v(acc, v0, w0);
    }

    float a8[8];
    #pragma unroll
    for (int i = 0; i < 4; ++i) { a8[2 * i] = acc[i].x; a8[2 * i + 1] = acc[i].y; }
    #pragma unroll
    for (int i = 0; i < 8; ++i) {            // combine the 4 edge-groups
        a8[i] += __shfl_xor(a8[i], 16, 64);
        a8[i] += __shfl_xor(a8[i], 32, 64);
    }

    if (g == 0) {
        if (RELU_BIAS) {
            const float4* b4 = (const float4*)biasf;
            float4 blo = b4[sub * 2], bhi = b4[sub * 2 + 1];
            a8[0] = fmaxf(a8[0] + blo.x, 0.f);
            a8[1] = fmaxf(a8[1] + blo.y, 0.f);
            a8[2] = fmaxf(a8[2] + blo.z, 0.f);
            a8[3] = fmaxf(a8[3] + blo.w, 0.f);
            a8[4] = fmaxf(a8[4] + bhi.x, 0.f);
            a8[5] = fmaxf(a8[5] + bhi.y, 0.f);
            a8[6] = fmaxf(a8[6] + bhi.z, 0.f);
            a8[7] = fmaxf(a8[7] + bhi.w, 0.f);
        }
        uint4 o;
        o.x = (unsigned)f2bf_raw(a8[0]) | ((unsigned)f2bf_raw(a8[1]) << 16);
        o.y = (unsigned)f2bf_raw(a8[2]) | ((unsigned)f2bf_raw(a8[3]) << 16);
        o.z = (unsigned)f2bf_raw(a8[4]) | ((unsigned)f2bf_raw(a8[5]) << 16);
        o.w = (unsigned)f2bf_raw(a8[6]) | ((unsigned)f2bf_raw(a8[7]) << 16);
        G4[selfoff] = o;
    }
}

// ---------------- GEMM2 (MFMA) + bias + log_softmax (runtime output dtype) ----------------

__global__ __launch_bounds__(256) void gemm2_mfma(const unsigned short* __restrict__ X,
                                                  const unsigned short* __restrict__ WB2,
                                                  const float* __restrict__ b2f,
                                                  void* __restrict__ OUTv, int nrows,
                                                  const int* __restrict__ flag) {
    __shared__ __align__(16) unsigned short Xs[128 * 136];
    const int t = threadIdx.x;
    const int r0 = blockIdx.x * 128;
    const int outf32 = *flag;

    const uint4* Xg = (const uint4*)X;
    #pragma unroll
    for (int i = 0; i < 8; ++i) {
        int idx = t + 256 * i;
        int row = idx >> 4, c8 = idx & 15;
        uint4 v = {0u, 0u, 0u, 0u};
        if (r0 + row < nrows) v = Xg[(size_t)(r0 + row) * 16 + c8];
        *reinterpret_cast<uint4*>(&Xs[row * 136 + c8 * 8]) = v;
    }
    __syncthreads();

    const int lane = t & 63, w = t >> 6;
    const int m0 = w * 32;
    short8 a[2][4];
    #pragma unroll
    for (int rt = 0; rt < 2; ++rt)
        #pragma unroll
        for (int kk = 0; kk < 4; ++kk)
            a[rt][kk] = *reinterpret_cast<const short8*>(
                &Xs[(m0 + rt * 16 + (lane & 15)) * 136 + kk * 32 + (lane >> 4) * 8]);

    short8 b[4][4];
    #pragma unroll
    for (int n = 0; n < 4; ++n)
        #pragma unroll
        for (int kk = 0; kk < 4; ++kk)
            b[n][kk] = *reinterpret_cast<const short8*>(
                WB2 + (size_t)((n * 4 + kk) * 64 + lane) * 8);

    f32x4 acc[2][4];
    #pragma unroll
    for (int rt = 0; rt < 2; ++rt)
        #pragma unroll
        for (int n = 0; n < 4; ++n) {
            acc[rt][n] = (f32x4){0.f, 0.f, 0.f, 0.f};
            #pragma unroll
            for (int kk = 0; kk < 4; ++kk)
                acc[rt][n] = __builtin_amdgcn_mfma_f32_16x16x32_bf16(
                    a[rt][kk], b[n][kk], acc[rt][n], 0, 0, 0);
        }

    float bc[4];
    #pragma unroll
    for (int n = 0; n < 4; ++n) bc[n] = b2f[n * 16 + (lane & 15)];
    #pragma unroll
    for (int rt = 0; rt < 2; ++rt)
        #pragma unroll
        for (int n = 0; n < 4; ++n)
            #pragma unroll
            for (int r = 0; r < 4; ++r) acc[rt][n][r] += bc[n];

    float lse[2][4];
    #pragma unroll
    for (int rt = 0; rt < 2; ++rt)
        #pragma unroll
        for (int r = 0; r < 4; ++r) {
            float m = fmaxf(fmaxf(acc[rt][0][r], acc[rt][1][r]),
                            fmaxf(acc[rt][2][r], acc[rt][3][r]));
            #pragma unroll
            for (int o = 1; o < 16; o <<= 1) m = fmaxf(m, __shfl_xor(m, o, 64));
            float s = __expf(acc[rt][0][r] - m) + __expf(acc[rt][1][r] - m) +
                      __expf(acc[rt][2][r] - m) + __expf(acc[rt][3][r] - m);
            #pragma unroll
            for (int o = 1; o < 16; o <<= 1) s += __shfl_xor(s, o, 64);
            lse[rt][r] = m + __logf(s);
        }

    const int colb = lane & 15, q = lane >> 4;
    #pragma unroll
    for (int rt = 0; rt < 2; ++rt)
        #pragma unroll
        for (int r = 0; r < 4; ++r) {
            int grow = r0 + m0 + rt * 16 + q * 4 + r;
            if (grow < nrows) {
                if (outf32) {
                    float* Of = (float*)OUTv;
                    #pragma unroll
                    for (int n = 0; n < 4; ++n)
                        Of[(size_t)grow * 64 + n * 16 + colb] = acc[rt][n][r] - lse[rt][r];
                } else {
                    unsigned short* Ob = (unsigned short*)OUTv;
                    #pragma unroll
                    for (int n = 0; n < 4; ++n)
                        Ob[(size_t)grow * 64 + n * 16 + colb] = f2bf_raw(acc[rt][n][r] - lse[rt][r]);
                }
            }
        }
}

// ---------------- launch ----------------

extern "C" void kernel_launch(void* const* d_in, const int* in_sizes, int n_in,
                              void* d_out, int out_size, void* d_ws, size_t ws_size,
                              hipStream_t stream) {
    const void* x  = d_in[0];
    const int*  ei = (const int*)d_in[1];
    const void* W1 = d_in[2];
    const void* b1 = d_in[3];
    const void* W2 = d_in[4];
    const void* b2 = d_in[5];

    const int N = in_sizes[0] / 128;
    const int E = in_sizes[1] / 2;
    const int* src = ei;
    const int* dst = ei + E;
    const int NBUK = (N + NPB - 1) / NPB;     // 391 for N=100K

    char* p = (char*)d_ws;
    auto alloc = [&](size_t bytes) { char* q = p; p += (bytes + 255) & ~255ull; return q; };
    int*   flag   = (int*)  alloc(4);
    uint2* nmeta  = (uint2*)alloc((size_t)N * 8);
    float* dinv   = (float*)alloc((size_t)N * 4);
    int*   bktcnt = (int*)  alloc((size_t)NBUK * 4);
    int*   bofs   = (int*)  alloc((size_t)(NBUK + 1) * 4);
    int*   bcur   = (int*)  alloc((size_t)NBUK * 4);
    float* b1f    = (float*)alloc(128 * 4);
    float* b2f    = (float*)alloc(64 * 4);
    unsigned short* WB1 = (unsigned short*)alloc(16384 * 2);
    unsigned short* WB2 = (unsigned short*)alloc(8192 * 2);
    unsigned* big = (unsigned*)alloc((size_t)N * 128 * 2);   // h1, later a2 (row-major)
    unsigned* packed = (unsigned*)d_out;          // 6.4 MB scratch in d_out (dead after csr_fine2)
    float*    wsrc   = (float*)d_out;             // reuses packed's space after it dies
    int*      csrc   = (int*)d_out + E;           // 6.4 MB scratch in d_out
    unsigned* g1 = (unsigned*)d_in[0];            // g1 into x's buffer (x dead after gemm1)
    (void)ws_size; (void)n_in; (void)out_size;

    hipMemsetAsync(bktcnt, 0, (size_t)NBUK * 4, stream);
    sniff_kernel<<<1, 1024, 0, stream>>>((const unsigned short*)W1, in_sizes[2], flag);
    prep_kernel<<<97, 256, 0, stream>>>(W1, W2, b1, b2, WB1, WB2, b1f, b2f, flag);
    const int MSB = (E + 4095) / 4096;
    ms_count_kernel<<<MSB, 256, 0, stream>>>(dst, bktcnt, E, NBUK);
    bscan_kernel<<<1, 1024, 0, stream>>>(bktcnt, bofs, bcur, NBUK, E);
    ms_scatter_kernel<<<MSB, 256, 0, stream>>>(src, dst, bcur, packed, E, NBUK);
    csr_fine2_kernel<<<NBUK, 256, 0, stream>>>(packed, bofs, nmeta, dinv, csrc, N);
    wsrc_kernel<<<(E + 255) / 256, 256, 0, stream>>>(csrc, dinv, wsrc, E);

    const int GB = (N + 127) / 128;
    gemm1_mfma<<<GB, 256, 0, stream>>>(x, WB1, (unsigned short*)big, N, flag);
    agg128_v5<true><<<(N + 1) / 2, 128, 0, stream>>>((const uint4*)big, nmeta, csrc, wsrc, b1f, (uint4*)g1, N);
    agg128_v5<false><<<(N + 1) / 2, 128, 0, stream>>>((const uint4*)g1, nmeta, csrc, wsrc, nullptr, (uint4*)big, N);
    gemm2_mfma<<<GB, 256, 0, stream>>>((const unsigned short*)big, WB2, b2f, d_out, N, flag);
}

// Round 5
// 312.390 us; speedup vs baseline: 1.0710x; 1.0636x over previous
//
#include <hip/hip_runtime.h>
#include <hip/hip_bf16.h>

typedef __hip_bfloat16 bf16;
typedef short short8 __attribute__((ext_vector_type(8)));
typedef float f32x4 __attribute__((ext_vector_type(4)));
typedef float f32x2 __attribute__((ext_vector_type(2)));

#define NPB 256          // nodes per bucket (coarse radix = dst>>8)
#define MAXBUK 1024      // supports N <= 262144

__device__ __forceinline__ float bf2f_raw(unsigned short u) {
    unsigned x = ((unsigned)u) << 16; float f; __builtin_memcpy(&f, &x, 4); return f;
}
__device__ __forceinline__ unsigned short f2bf_raw(float f) {   // RNE
    unsigned u; __builtin_memcpy(&u, &f, 4);
    u += 0x7FFFu + ((u >> 16) & 1u);
    return (unsigned short)(u >> 16);
}
__device__ __forceinline__ float lo_f(unsigned u) {
    unsigned x = u << 16; float f; __builtin_memcpy(&f, &x, 4); return f;
}
__device__ __forceinline__ float hi_f(unsigned u) {
    unsigned x = u & 0xffff0000u; float f; __builtin_memcpy(&f, &x, 4); return f;
}

// ---------------- dtype sniffer: flag=1 if float arrays are f32, 0 if bf16 ----------------

__global__ __launch_bounds__(1024) void sniff_kernel(const unsigned short* __restrict__ w,
                                                     int nshorts, int* __restrict__ flag) {
    __shared__ int red[1024];
    const int t = threadIdx.x;
    int c = 0;
    for (int i = t; i < nshorts; i += 1024) {
        unsigned e = (w[i] >> 7) & 0xFFu;
        if (e >= 140u || (e >= 1u && e <= 40u)) c++;
    }
    red[t] = c;
    __syncthreads();
    for (int o = 512; o > 0; o >>= 1) {
        if (t < o) red[t] += red[t + o];
        __syncthreads();
    }
    if (t == 0) *flag = (red[0] > nshorts / 8) ? 1 : 0;
}

// ---------------- prep: biases->f32; W1/W2 -> MFMA B-fragment-linear bf16 ----------------
// Fragment (16x16x32 bf16 B-operand): lane l holds B[k=(l>>4)*8+j][n=l&15], j=0..7.

__global__ __launch_bounds__(256) void prep_kernel(const void* __restrict__ W1p,
                                                   const void* __restrict__ W2p,
                                                   const void* __restrict__ b1p,
                                                   const void* __restrict__ b2p,
                                                   unsigned short* __restrict__ WB1,
                                                   unsigned short* __restrict__ WB2,
                                                   float* __restrict__ b1f,
                                                   float* __restrict__ b2f,
                                                   const int* __restrict__ flag) {
    const int isf32 = *flag;
    const int t = blockIdx.x * 256 + threadIdx.x;
    const int T1 = 16384, T2 = 8192;
    if (t < T1) {
        int j = t & 7, l = (t >> 3) & 63, f = t >> 9;
        int n = f >> 2, kk = f & 3;
        int k = kk * 32 + (l >> 4) * 8 + j;
        int col = n * 16 + (l & 15);
        WB1[t] = isf32 ? f2bf_raw(((const float*)W1p)[k * 128 + col])
                       : ((const unsigned short*)W1p)[k * 128 + col];
    } else if (t < T1 + T2) {
        int o = t - T1;
        int j = o & 7, l = (o >> 3) & 63, f = o >> 9;
        int n = f >> 2, kk = f & 3;
        int k = kk * 32 + (l >> 4) * 8 + j;
        int col = n * 16 + (l & 15);
        WB2[o] = isf32 ? f2bf_raw(((const float*)W2p)[k * 64 + col])
                       : ((const unsigned short*)W2p)[k * 64 + col];
    } else if (t < T1 + T2 + 128) {
        int o = t - T1 - T2;
        b1f[o] = isf32 ? ((const float*)b1p)[o] : bf2f_raw(((const unsigned short*)b1p)[o]);
    } else if (t < T1 + T2 + 192) {
        int o = t - T1 - T2 - 128;
        b2f[o] = isf32 ? ((const float*)b2p)[o] : bf2f_raw(((const unsigned short*)b2p)[o]);
    }
}

// ---------------- CSR build, bucket-granular ----------------
// 1) ms_count: per-block LDS bucket histogram -> global bucket totals.

__global__ __launch_bounds__(256) void ms_count_kernel(const int* __restrict__ dst,
                                                       int* __restrict__ bktcnt,
                                                       int E, int nbuk) {
    __shared__ int cnt[MAXBUK];
    const int t = threadIdx.x;
    const int e0 = blockIdx.x * 4096;
    const int e1 = min(E, e0 + 4096);
    for (int b = t; b < nbuk; b += 256) cnt[b] = 0;
    __syncthreads();
    for (int e = e0 + t; e < e1; e += 256) atomicAdd(&cnt[dst[e] >> 8], 1);
    __syncthreads();
    for (int b = t; b < nbuk; b += 256) {
        int c = cnt[b];
        if (c) atomicAdd(&bktcnt[b], c);
    }
}

// 2) bscan: exclusive scan of bucket totals -> bofs/bcur.
__global__ __launch_bounds__(1024) void bscan_kernel(const int* __restrict__ bktcnt,
                                                     int* __restrict__ bofs,
                                                     int* __restrict__ bcur,
                                                     int nbuk, int total) {
    __shared__ int ps[1024];
    const int t = threadIdx.x;
    int v = (t < nbuk) ? bktcnt[t] : 0;
    ps[t] = v;
    __syncthreads();
    for (int o = 1; o < 1024; o <<= 1) {
        int u = (t >= o) ? ps[t - o] : 0;
        __syncthreads();
        ps[t] += u;
        __syncthreads();
    }
    if (t < nbuk) {
        int ex = ps[t] - v;
        bofs[t] = ex;
        bcur[t] = ex;
    }
    if (t == 0) bofs[nbuk] = total;
}

// 3) ms_scatter: bin edges into per-bucket contiguous chunks (packed = (dst&255)<<24 | src).
__global__ __launch_bounds__(256) void ms_scatter_kernel(const int* __restrict__ src,
                                                         const int* __restrict__ dst,
                                                         int* __restrict__ bcur,
                                                         unsigned* __restrict__ packed,
                                                         int E, int nbuk) {
    __shared__ int cnt[MAXBUK];
    __shared__ int gbase[MAXBUK];
    const int t = threadIdx.x;
    const int e0 = blockIdx.x * 4096;
    const int e1 = min(E, e0 + 4096);
    for (int b = t; b < nbuk; b += 256) cnt[b] = 0;
    __syncthreads();
    for (int e = e0 + t; e < e1; e += 256) atomicAdd(&cnt[dst[e] >> 8], 1);
    __syncthreads();
    for (int b = t; b < nbuk; b += 256) {
        int c = cnt[b];
        gbase[b] = c ? atomicAdd(&bcur[b], c) : 0;
        cnt[b] = 0;
    }
    __syncthreads();
    for (int e = e0 + t; e < e1; e += 256) {
        int d = dst[e];
        int b = d >> 8;
        int r = atomicAdd(&cnt[b], 1);
        packed[gbase[b] + r] = ((unsigned)(d & 255) << 24) | (unsigned)src[e];
    }
}

// 4) csr_fine2: one block per bucket. Local histogram -> per-node nmeta {base,deg} + dinv; place edges.
__global__ __launch_bounds__(256) void csr_fine2_kernel(const unsigned* __restrict__ packed,
                                                        const int* __restrict__ bofs,
                                                        uint2* __restrict__ nmeta,
                                                        float* __restrict__ dinv,
                                                        int* __restrict__ csrc, int n) {
    __shared__ int cnt2[NPB];
    __shared__ int cur[NPB];
    const int t = threadIdx.x;
    const int b = blockIdx.x;
    const int node0 = b << 8;
    const int nn = min(NPB, n - node0);
    cnt2[t] = 0;
    __syncthreads();
    const int beg = bofs[b], end = bofs[b + 1];
    for (int i = beg + t; i < end; i += 256) atomicAdd(&cnt2[packed[i] >> 24], 1);
    __syncthreads();
    int c = cnt2[t];
    cur[t] = c;
    __syncthreads();
    for (int o = 1; o < 256; o <<= 1) {        // inclusive scan over 256 local counts
        int u = (t >= o) ? cur[t - o] : 0;
        __syncthreads();
        cur[t] += u;
        __syncthreads();
    }
    const int base = beg + cur[t] - c;          // exclusive
    if (t < nn) {
        nmeta[node0 + t] = make_uint2((unsigned)base, (unsigned)c);
        dinv[node0 + t] = rsqrtf((float)(c + 1));
    }
    __syncthreads();
    cur[t] = base;
    __syncthreads();
    for (int i = beg + t; i < end; i += 256) {
        unsigned u = packed[i];
        int pos = atomicAdd(&cur[u >> 24], 1);
        csrc[pos] = (int)(u & 0xFFFFFFu);
    }
}

// 5) wsrc: per-edge source normalization weight, wsrc[j] = dinv[csrc[j]].
__global__ __launch_bounds__(256) void wsrc_kernel(const int* __restrict__ csrc,
                                                   const float* __restrict__ dinv,
                                                   float* __restrict__ wsrc, int E) {
    int i = blockIdx.x * 256 + threadIdx.x;
    if (i < E) wsrc[i] = dinv[csrc[i]];
}

// ---------------- GEMM1 (MFMA): H[nrows x 128] = X * W1, bf16 out (runtime dtype) ----------------

__global__ __launch_bounds__(256) void gemm1_mfma(const void* __restrict__ Xp,
                                                  const unsigned short* __restrict__ WB1,
                                                  unsigned short* __restrict__ H, int nrows,
                                                  const int* __restrict__ flag) {
    __shared__ __align__(16) unsigned short Xs[128 * 136];
    __shared__ __align__(16) unsigned short Cs[128 * 68];
    const int t = threadIdx.x;
    const int r0 = blockIdx.x * 128;
    const int isf32 = *flag;

    if (isf32) {
        const float4* Xg = (const float4*)Xp;
        #pragma unroll
        for (int i = 0; i < 16; ++i) {
            int idx = t + 256 * i;
            int row = idx >> 5, c4 = idx & 31;
            float4 v = {0.f, 0.f, 0.f, 0.f};
            if (r0 + row < nrows) v = Xg[(size_t)(r0 + row) * 32 + c4];
            unsigned lo = (unsigned)f2bf_raw(v.x) | ((unsigned)f2bf_raw(v.y) << 16);
            unsigned hi = (unsigned)f2bf_raw(v.z) | ((unsigned)f2bf_raw(v.w) << 16);
            *reinterpret_cast<uint2*>(&Xs[row * 136 + c4 * 4]) = make_uint2(lo, hi);
        }
    } else {
        const uint4* Xg = (const uint4*)Xp;
        #pragma unroll
        for (int i = 0; i < 8; ++i) {
            int idx = t + 256 * i;
            int row = idx >> 4, c8 = idx & 15;
            uint4 v = {0u, 0u, 0u, 0u};
            if (r0 + row < nrows) v = Xg[(size_t)(r0 + row) * 16 + c8];
            *reinterpret_cast<uint4*>(&Xs[row * 136 + c8 * 8]) = v;
        }
    }
    __syncthreads();

    const int lane = t & 63, w = t >> 6;
    const int m0 = w * 32;
    short8 a[2][4];
    #pragma unroll
    for (int rt = 0; rt < 2; ++rt)
        #pragma unroll
        for (int kk = 0; kk < 4; ++kk)
            a[rt][kk] = *reinterpret_cast<const short8*>(
                &Xs[(m0 + rt * 16 + (lane & 15)) * 136 + kk * 32 + (lane >> 4) * 8]);

    for (int p = 0; p < 2; ++p) {
        short8 b[4][4];
        #pragma unroll
        for (int n = 0; n < 4; ++n)
            #pragma unroll
            for (int kk = 0; kk < 4; ++kk)
                b[n][kk] = *reinterpret_cast<const short8*>(
                    WB1 + (size_t)(((p * 4 + n) * 4 + kk) * 64 + lane) * 8);
        f32x4 acc[2][4];
        #pragma unroll
        for (int rt = 0; rt < 2; ++rt)
            #pragma unroll
            for (int n = 0; n < 4; ++n) {
                acc[rt][n] = (f32x4){0.f, 0.f, 0.f, 0.f};
                #pragma unroll
                for (int kk = 0; kk < 4; ++kk)
                    acc[rt][n] = __builtin_amdgcn_mfma_f32_16x16x32_bf16(
                        a[rt][kk], b[n][kk], acc[rt][n], 0, 0, 0);
            }
        if (p) __syncthreads();
        #pragma unroll
        for (int rt = 0; rt < 2; ++rt)
            #pragma unroll
            for (int n = 0; n < 4; ++n)
                #pragma unroll
                for (int r = 0; r < 4; ++r) {
                    int row = m0 + rt * 16 + (lane >> 4) * 4 + r;
                    Cs[row * 68 + n * 16 + (lane & 15)] = f2bf_raw(acc[rt][n][r]);
                }
        __syncthreads();
        #pragma unroll
        for (int i = 0; i < 8; ++i) {
            int idx = t + 256 * i;
            int row = idx >> 4, c4 = idx & 15;
            if (r0 + row < nrows) {
                uint2 v = *reinterpret_cast<const uint2*>(&Cs[row * 68 + c4 * 4]);
                *reinterpret_cast<uint2*>(H + (size_t)(r0 + row) * 128 + p * 64 + c4 * 4) = v;
            }
        }
        if (!p) __syncthreads();
    }
}

// ---------------- Aggregation v5 (layer 1): wave-per-node, 16/8/4/tail cascade, 128ch ----------------

__device__ __forceinline__ void acc8v(f32x2* acc, uint4 v, float w) {
    f32x2 wv = {w, w};
    acc[0] += (f32x2){lo_f(v.x), hi_f(v.x)} * wv;
    acc[1] += (f32x2){lo_f(v.y), hi_f(v.y)} * wv;
    acc[2] += (f32x2){lo_f(v.z), hi_f(v.z)} * wv;
    acc[3] += (f32x2){lo_f(v.w), hi_f(v.w)} * wv;
}

__global__ __launch_bounds__(128) void agg128_v5(const uint4* __restrict__ H4,
                                                 const uint2* __restrict__ nmeta,
                                                 const int* __restrict__ csrc,
                                                 const float* __restrict__ wsrc,
                                                 const float* __restrict__ biasf,
                                                 uint4* __restrict__ G4, int n) {
    const int lane = threadIdx.x & 63;
    const int g = lane >> 4;
    const int sub = lane & 15;
    const int node = blockIdx.x * 2 + (threadIdx.x >> 6);
    if (node >= n) return;

    const unsigned selfoff = ((unsigned)node << 4) + (unsigned)sub;
    uint4 vself = H4[selfoff];

    const uint2 meta = nmeta[node];
    const int base = (int)meta.x;
    const int cnt = (int)meta.y;
    const int end = base + cnt;
    const float di = rsqrtf((float)(cnt + 1));

    f32x2 acc[4];
    {
        const float ws = (g == 0) ? di * di : 0.f;
        acc[0] = (f32x2){ws * lo_f(vself.x), ws * hi_f(vself.x)};
        acc[1] = (f32x2){ws * lo_f(vself.y), ws * hi_f(vself.y)};
        acc[2] = (f32x2){ws * lo_f(vself.z), ws * hi_f(vself.z)};
        acc[3] = (f32x2){ws * lo_f(vself.w), ws * hi_f(vself.w)};
    }

    int j = base;
    for (; j + 15 < end; j += 16) {
        int s0 = csrc[j + g];
        int s1 = csrc[j + 4 + g];
        int s2 = csrc[j + 8 + g];
        int s3 = csrc[j + 12 + g];
        uint4 v0 = H4[((unsigned)s0 << 4) + sub];
        uint4 v1 = H4[((unsigned)s1 << 4) + sub];
        uint4 v2 = H4[((unsigned)s2 << 4) + sub];
        uint4 v3 = H4[((unsigned)s3 << 4) + sub];
        float w0 = di * wsrc[j + g];
        float w1 = di * wsrc[j + 4 + g];
        float w2 = di * wsrc[j + 8 + g];
        float w3 = di * wsrc[j + 12 + g];
        acc8v(acc, v0, w0);
        acc8v(acc, v1, w1);
        acc8v(acc, v2, w2);
        acc8v(acc, v3, w3);
    }
    for (; j + 7 < end; j += 8) {
        int s0 = csrc[j + g];
        int s1 = csrc[j + 4 + g];
        uint4 v0 = H4[((unsigned)s0 << 4) + sub];
        uint4 v1 = H4[((unsigned)s1 << 4) + sub];
        float w0 = di * wsrc[j + g];
        float w1 = di * wsrc[j + 4 + g];
        acc8v(acc, v0, w0);
        acc8v(acc, v1, w1);
    }
    for (; j + 3 < end; j += 4) {
        int s0 = csrc[j + g];
        uint4 v0 = H4[((unsigned)s0 << 4) + sub];
        float w0 = di * wsrc[j + g];
        acc8v(acc, v0, w0);
    }
    if (j + g < end) {
        int s0 = csrc[j + g];
        uint4 v0 = H4[((unsigned)s0 << 4) + sub];
        float w0 = di * wsrc[j + g];
        acc8v(acc, v0, w0);
    }

    float a8[8];
    #pragma unroll
    for (int i = 0; i < 4; ++i) { a8[2 * i] = acc[i].x; a8[2 * i + 1] = acc[i].y; }
    #pragma unroll
    for (int i = 0; i < 8; ++i) {
        a8[i] += __shfl_xor(a8[i], 16, 64);
        a8[i] += __shfl_xor(a8[i], 32, 64);
    }

    if (g == 0) {
        const float4* b4 = (const float4*)biasf;
        float4 blo = b4[sub * 2], bhi = b4[sub * 2 + 1];
        a8[0] = fmaxf(a8[0] + blo.x, 0.f);
        a8[1] = fmaxf(a8[1] + blo.y, 0.f);
        a8[2] = fmaxf(a8[2] + blo.z, 0.f);
        a8[3] = fmaxf(a8[3] + blo.w, 0.f);
        a8[4] = fmaxf(a8[4] + bhi.x, 0.f);
        a8[5] = fmaxf(a8[5] + bhi.y, 0.f);
        a8[6] = fmaxf(a8[6] + bhi.z, 0.f);
        a8[7] = fmaxf(a8[7] + bhi.w, 0.f);
        uint4 o;
        o.x = (unsigned)f2bf_raw(a8[0]) | ((unsigned)f2bf_raw(a8[1]) << 16);
        o.y = (unsigned)f2bf_raw(a8[2]) | ((unsigned)f2bf_raw(a8[3]) << 16);
        o.z = (unsigned)f2bf_raw(a8[4]) | ((unsigned)f2bf_raw(a8[5]) << 16);
        o.w = (unsigned)f2bf_raw(a8[6]) | ((unsigned)f2bf_raw(a8[7]) << 16);
        G4[selfoff] = o;
    }
}

// ---------------- GEMM2b (MFMA): T[nrows x 64] = G1 * W2, bf16 out, NO bias ----------------
// Layer-2 flip: transform 128->64 BEFORE aggregating, halving agg-2 gather bytes.

__global__ __launch_bounds__(256) void gemm2b_mfma(const unsigned short* __restrict__ X,
                                                   const unsigned short* __restrict__ WB2,
                                                   unsigned short* __restrict__ T, int nrows) {
    __shared__ __align__(16) unsigned short Xs[128 * 136];
    __shared__ __align__(16) unsigned short Cs[128 * 68];
    const int t = threadIdx.x;
    const int r0 = blockIdx.x * 128;

    const uint4* Xg = (const uint4*)X;
    #pragma unroll
    for (int i = 0; i < 8; ++i) {
        int idx = t + 256 * i;
        int row = idx >> 4, c8 = idx & 15;
        uint4 v = {0u, 0u, 0u, 0u};
        if (r0 + row < nrows) v = Xg[(size_t)(r0 + row) * 16 + c8];
        *reinterpret_cast<uint4*>(&Xs[row * 136 + c8 * 8]) = v;
    }
    __syncthreads();

    const int lane = t & 63, w = t >> 6;
    const int m0 = w * 32;
    short8 a[2][4];
    #pragma unroll
    for (int rt = 0; rt < 2; ++rt)
        #pragma unroll
        for (int kk = 0; kk < 4; ++kk)
            a[rt][kk] = *reinterpret_cast<const short8*>(
                &Xs[(m0 + rt * 16 + (lane & 15)) * 136 + kk * 32 + (lane >> 4) * 8]);

    short8 b[4][4];
    #pragma unroll
    for (int n = 0; n < 4; ++n)
        #pragma unroll
        for (int kk = 0; kk < 4; ++kk)
            b[n][kk] = *reinterpret_cast<const short8*>(
                WB2 + (size_t)((n * 4 + kk) * 64 + lane) * 8);

    f32x4 acc[2][4];
    #pragma unroll
    for (int rt = 0; rt < 2; ++rt)
        #pragma unroll
        for (int n = 0; n < 4; ++n) {
            acc[rt][n] = (f32x4){0.f, 0.f, 0.f, 0.f};
            #pragma unroll
            for (int kk = 0; kk < 4; ++kk)
                acc[rt][n] = __builtin_amdgcn_mfma_f32_16x16x32_bf16(
                    a[rt][kk], b[n][kk], acc[rt][n], 0, 0, 0);
        }

    __syncthreads();
    #pragma unroll
    for (int rt = 0; rt < 2; ++rt)
        #pragma unroll
        for (int n = 0; n < 4; ++n)
            #pragma unroll
            for (int r = 0; r < 4; ++r) {
                int row = m0 + rt * 16 + (lane >> 4) * 4 + r;
                Cs[row * 68 + n * 16 + (lane & 15)] = f2bf_raw(acc[rt][n][r]);
            }
    __syncthreads();
    #pragma unroll
    for (int i = 0; i < 8; ++i) {
        int idx = t + 256 * i;
        int row = idx >> 4, c4 = idx & 15;
        if (r0 + row < nrows) {
            uint2 v = *reinterpret_cast<const uint2*>(&Cs[row * 68 + c4 * 4]);
            *reinterpret_cast<uint2*>(T + (size_t)(r0 + row) * 64 + c4 * 4) = v;
        }
    }
}

// ---------------- Aggregation 2 + bias + log_softmax (64 ch): 8 lanes/edge, 8 edge-groups ----------------
// Lane l: group g=l>>3 handles edge slot j+g (8 edges/round in flight); sub=l&7 covers 16B chunk
// of the 128B row. Final reduce: shfl_xor 8/16/32; softmax within the 8-lane group (xor 1/2/4).

__global__ __launch_bounds__(128) void agg64_final(const uint4* __restrict__ T4,
                                                   const uint2* __restrict__ nmeta,
                                                   const int* __restrict__ csrc,
                                                   const float* __restrict__ wsrc,
                                                   const float* __restrict__ b2f,
                                                   void* __restrict__ OUTv, int n,
                                                   const int* __restrict__ flag) {
    const int lane = threadIdx.x & 63;
    const int g = lane >> 3;
    const int sub = lane & 7;
    const int node = blockIdx.x * 2 + (threadIdx.x >> 6);
    if (node >= n) return;
    const int outf32 = *flag;

    const unsigned selfoff = ((unsigned)node << 3) + (unsigned)sub;
    uint4 vself = T4[selfoff];

    const uint2 meta = nmeta[node];
    const int base = (int)meta.x;
    const int cnt = (int)meta.y;
    const int end = base + cnt;
    const float di = rsqrtf((float)(cnt + 1));

    f32x2 acc[4];
    {
        const float ws = (g == 0) ? di * di : 0.f;
        acc[0] = (f32x2){ws * lo_f(vself.x), ws * hi_f(vself.x)};
        acc[1] = (f32x2){ws * lo_f(vself.y), ws * hi_f(vself.y)};
        acc[2] = (f32x2){ws * lo_f(vself.z), ws * hi_f(vself.z)};
        acc[3] = (f32x2){ws * lo_f(vself.w), ws * hi_f(vself.w)};
    }

    int j = base;
    for (; j + 15 < end; j += 16) {          // 16 edges, 2 gathers per lane in flight
        int s0 = csrc[j + g];
        int s1 = csrc[j + 8 + g];
        uint4 v0 = T4[((unsigned)s0 << 3) + sub];
        uint4 v1 = T4[((unsigned)s1 << 3) + sub];
        float w0 = di * wsrc[j + g];
        float w1 = di * wsrc[j + 8 + g];
        acc8v(acc, v0, w0);
        acc8v(acc, v1, w1);
    }
    for (; j + 7 < end; j += 8) {            // 8 edges
        int s0 = csrc[j + g];
        uint4 v0 = T4[((unsigned)s0 << 3) + sub];
        float w0 = di * wsrc[j + g];
        acc8v(acc, v0, w0);
    }
    if (j + g < end) {                       // tail (<8 edges), group-predicated
        int s0 = csrc[j + g];
        uint4 v0 = T4[((unsigned)s0 << 3) + sub];
        float w0 = di * wsrc[j + g];
        acc8v(acc, v0, w0);
    }

    float a8[8];
    #pragma unroll
    for (int i = 0; i < 4; ++i) { a8[2 * i] = acc[i].x; a8[2 * i + 1] = acc[i].y; }
    #pragma unroll
    for (int i = 0; i < 8; ++i) {            // combine the 8 edge-groups
        a8[i] += __shfl_xor(a8[i], 8, 64);
        a8[i] += __shfl_xor(a8[i], 16, 64);
        a8[i] += __shfl_xor(a8[i], 32, 64);
    }

    if (g == 0) {                            // lanes 0..7 hold the full 64-ch row
        const float4* b4 = (const float4*)b2f;
        float4 blo = b4[sub * 2], bhi = b4[sub * 2 + 1];
        a8[0] += blo.x; a8[1] += blo.y; a8[2] += blo.z; a8[3] += blo.w;
        a8[4] += bhi.x; a8[5] += bhi.y; a8[6] += bhi.z; a8[7] += bhi.w;

        float m = fmaxf(fmaxf(fmaxf(a8[0], a8[1]), fmaxf(a8[2], a8[3])),
                        fmaxf(fmaxf(a8[4], a8[5]), fmaxf(a8[6], a8[7])));
        m = fmaxf(m, __shfl_xor(m, 1, 64));
        m = fmaxf(m, __shfl_xor(m, 2, 64));
        m = fmaxf(m, __shfl_xor(m, 4, 64));
        float s = __expf(a8[0] - m) + __expf(a8[1] - m) + __expf(a8[2] - m) + __expf(a8[3] - m) +
                  __expf(a8[4] - m) + __expf(a8[5] - m) + __expf(a8[6] - m) + __expf(a8[7] - m);
        s += __shfl_xor(s, 1, 64);
        s += __shfl_xor(s, 2, 64);
        s += __shfl_xor(s, 4, 64);
        const float lse = m + __logf(s);

        if (outf32) {
            float4* Of = (float4*)OUTv;
            float4 o0 = {a8[0] - lse, a8[1] - lse, a8[2] - lse, a8[3] - lse};
            float4 o1 = {a8[4] - lse, a8[5] - lse, a8[6] - lse, a8[7] - lse};
            Of[(size_t)node * 16 + sub * 2] = o0;
            Of[(size_t)node * 16 + sub * 2 + 1] = o1;
        } else {
            uint4 o;
            o.x = (unsigned)f2bf_raw(a8[0] - lse) | ((unsigned)f2bf_raw(a8[1] - lse) << 16);
            o.y = (unsigned)f2bf_raw(a8[2] - lse) | ((unsigned)f2bf_raw(a8[3] - lse) << 16);
            o.z = (unsigned)f2bf_raw(a8[4] - lse) | ((unsigned)f2bf_raw(a8[5] - lse) << 16);
            o.w = (unsigned)f2bf_raw(a8[6] - lse) | ((unsigned)f2bf_raw(a8[7] - lse) << 16);
            ((uint4*)OUTv)[(size_t)node * 8 + sub] = o;
        }
    }
}

// ---------------- launch ----------------

extern "C" void kernel_launch(void* const* d_in, const int* in_sizes, int n_in,
                              void* d_out, int out_size, void* d_ws, size_t ws_size,
                              hipStream_t stream) {
    const void* x  = d_in[0];
    const int*  ei = (const int*)d_in[1];
    const void* W1 = d_in[2];
    const void* b1 = d_in[3];
    const void* W2 = d_in[4];
    const void* b2 = d_in[5];

    const int N = in_sizes[0] / 128;
    const int E = in_sizes[1] / 2;
    const int* src = ei;
    const int* dst = ei + E;
    const int NBUK = (N + NPB - 1) / NPB;     // 391 for N=100K

    char* p = (char*)d_ws;
    auto alloc = [&](size_t bytes) { char* q = p; p += (bytes + 255) & ~255ull; return q; };
    int*   flag   = (int*)  alloc(4);
    uint2* nmeta  = (uint2*)alloc((size_t)N * 8);
    float* dinv   = (float*)alloc((size_t)N * 4);
    int*   bktcnt = (int*)  alloc((size_t)NBUK * 4);
    int*   bofs   = (int*)  alloc((size_t)(NBUK + 1) * 4);
    int*   bcur   = (int*)  alloc((size_t)NBUK * 4);
    float* b1f    = (float*)alloc(128 * 4);
    float* b2f    = (float*)alloc(64 * 4);
    unsigned short* WB1 = (unsigned short*)alloc(16384 * 2);
    unsigned short* WB2 = (unsigned short*)alloc(8192 * 2);
    unsigned* big = (unsigned*)alloc((size_t)N * 128 * 2);   // H (25.6 MB), later T (12.8 MB)
    unsigned* packed = (unsigned*)d_out;          // 6.4 MB scratch in d_out (dead after csr_fine2)
    int*      csrc   = (int*)d_in[1];             // overwrites src (dead after ms_scatter)
    float*    wsrc   = (float*)d_in[1] + E;       // overwrites dst (dead after ms_scatter)
    unsigned* g1 = (unsigned*)d_in[0];            // g1 into x's buffer (x dead after gemm1)
    unsigned short* T = (unsigned short*)big;     // T overwrites H (dead after agg1)
    (void)ws_size; (void)n_in; (void)out_size;

    hipMemsetAsync(bktcnt, 0, (size_t)NBUK * 4, stream);
    sniff_kernel<<<1, 1024, 0, stream>>>((const unsigned short*)W1, in_sizes[2], flag);
    prep_kernel<<<97, 256, 0, stream>>>(W1, W2, b1, b2, WB1, WB2, b1f, b2f, flag);
    const int MSB = (E + 4095) / 4096;
    ms_count_kernel<<<MSB, 256, 0, stream>>>(dst, bktcnt, E, NBUK);
    bscan_kernel<<<1, 1024, 0, stream>>>(bktcnt, bofs, bcur, NBUK, E);
    ms_scatter_kernel<<<MSB, 256, 0, stream>>>(src, dst, bcur, packed, E, NBUK);
    csr_fine2_kernel<<<NBUK, 256, 0, stream>>>(packed, bofs, nmeta, dinv, csrc, N);
    wsrc_kernel<<<(E + 255) / 256, 256, 0, stream>>>(csrc, dinv, wsrc, E);

    const int GB = (N + 127) / 128;
    gemm1_mfma<<<GB, 256, 0, stream>>>(x, WB1, (unsigned short*)big, N, flag);
    agg128_v5<<<(N + 1) / 2, 128, 0, stream>>>((const uint4*)big, nmeta, csrc, wsrc, b1f, (uint4*)g1, N);
    gemm2b_mfma<<<GB, 256, 0, stream>>>((const unsigned short*)g1, WB2, T, N);
    agg64_final<<<(N + 1) / 2, 128, 0, stream>>>((const uint4*)T, nmeta, csrc, wsrc, b2f, d_out, N, flag);
}